// Round 3
// baseline (127.191 us; speedup 1.0000x reference)
//
#include <hip/hip_runtime.h>

// Problem constants: N=16, C=256, K=6, M=22, Ho=17
#define NB   16
#define CC   256
#define KK   6
#define MM   22
#define HO   17           // M - K + 1
#define NPQ  (HO*HO)      // 289 outputs per batch image
#define TOT  (NB*NPQ)     // 4624 total outputs
#define CHN  8            // channels per block
#define CGRP (CC/CHN)     // 32 channel-groups
#define XPC  (MM*MM)      // 484 x-elements per channel
#define ZPC  (KK*KK)      // 36 z-elements per channel
#define XSTR 24           // padded LDS row stride (16B-aligned rows)
#define XCH  548          // padded LDS channel stride: %32==4 (bank spread), %4==0
#define RCH  292          // reduction buffer channel stride: %32==4

// ws layout (float words). cnt[17] at word 0 (memset 68 B each launch).
#define PART_OFF  64                      // 256 B in: part[n][cg][289]
#define PART_SZ   (NB*CGRP*NPQ)           // 147968
#define ACC_OFF   (PART_OFF + PART_SZ)    // 148032 (x4 B = 16B aligned)
#define STATS_OFF (ACC_OFF + TOT)         // 152656 (x4 B = 8B aligned) : double[32]

// One kernel does everything via the last-arriver pattern:
//   phase 1: all 512 blocks  — register-tiled correlation -> partials
//   phase 2: last block per batch (16) — sum 32 partials, batch stats (double)
//   phase 3: last of those 16         — global BN + write out
__global__ __launch_bounds__(256) void fused_kernel(
    const float* __restrict__ z, const float* __restrict__ x,
    const float* __restrict__ w, const float* __restrict__ bnw,
    const float* __restrict__ bnb, float* __restrict__ ws,
    float* __restrict__ out)
{
    __shared__ float  szw[CHN * ZPC];    // w_c * sqrt(z)
    __shared__ float  sx [CHN * XCH];    // sqrt(x), padded
    __shared__ float  red[CHN * RCH];    // per-channel row results
    __shared__ double sred[8];           // per-wave double stats
    __shared__ int    flag;
    __shared__ float  fstat[2];

    unsigned int* cnt   = (unsigned int*)ws;     // cnt[0..15] per batch, cnt[16] global
    float*  part  = ws + PART_OFF;
    float*  acc   = ws + ACC_OFF;
    double* dstat = (double*)(ws + STATS_OFF);

    const int b  = blockIdx.x;
    const int n  = b >> 5;               // / CGRP
    const int cg = b & 31;               // % CGRP
    const int c0 = cg * CHN;
    const int t  = threadIdx.x;

    // ---------------- phase 1: correlation ----------------
    const float* zb = z + (size_t)(n * CC + c0) * ZPC;
    const float* xb = x + (size_t)(n * CC + c0) * XPC;

    for (int e = t; e < CHN * ZPC; e += 256) {
        int c = e / ZPC;
        szw[e] = sqrtf(zb[e]) * w[c0 + c];
    }
    {
        const float2* xb2 = reinterpret_cast<const float2*>(xb);
        for (int e = t; e < CHN * XPC / 2; e += 256) {   // 1936 float2
            int ch  = e / 242;
            int r   = e - ch * 242;
            int row = r / 11;
            int col = (r - row * 11) * 2;
            float2 v = xb2[e];
            float* dst = &sx[ch * XCH + row * XSTR + col];
            dst[0] = sqrtf(v.x);
            dst[1] = sqrtf(v.y);
        }
    }
    __syncthreads();

    if (t < HO * CHN) {                  // 136 active threads
        const int p  = t >> 3;
        const int ch = t & 7;

        float zr[36];
        const float4* z4 = reinterpret_cast<const float4*>(&szw[ch * ZPC]);
        #pragma unroll
        for (int k = 0; k < 9; ++k) {
            float4 v = z4[k];
            zr[4*k] = v.x; zr[4*k+1] = v.y; zr[4*k+2] = v.z; zr[4*k+3] = v.w;
        }

        float a[HO];
        #pragma unroll
        for (int q = 0; q < HO; ++q) a[q] = 0.f;

        #pragma unroll
        for (int i = 0; i < KK; ++i) {
            float xr[24];
            const float4* row4 =
                reinterpret_cast<const float4*>(&sx[ch * XCH + (p + i) * XSTR]);
            #pragma unroll
            for (int k = 0; k < 6; ++k) {
                float4 v = row4[k];
                xr[4*k] = v.x; xr[4*k+1] = v.y; xr[4*k+2] = v.z; xr[4*k+3] = v.w;
            }
            #pragma unroll
            for (int j = 0; j < KK; ++j) {
                float zv = zr[i * KK + j];
                #pragma unroll
                for (int q = 0; q < HO; ++q)
                    a[q] += zv * xr[q + j];
            }
        }
        float* rr = &red[ch * RCH + p * HO];
        #pragma unroll
        for (int q = 0; q < HO; ++q) rr[q] = a[q];
    }
    __syncthreads();

    float* pb = part + ((size_t)n * CGRP + cg) * NPQ;
    for (int idx = t; idx < NPQ; idx += 256) {
        float s = 0.f;
        #pragma unroll
        for (int ch = 0; ch < CHN; ++ch) s += red[ch * RCH + idx];
        pb[idx] = s;
    }

    // release partials, last block of this batch proceeds
    __threadfence();
    __syncthreads();
    if (t == 0) flag = (atomicAdd(&cnt[n], 1u) == CGRP - 1) ? 1 : 0;
    __syncthreads();
    if (!flag) return;
    __threadfence();   // acquire

    // ---------------- phase 2: per-batch reduction + stats ----------------
    const float* pbase = part + (size_t)n * CGRP * NPQ;
    double ls = 0.0, ls2 = 0.0;
    for (int i = t; i < NPQ; i += 256) {
        float s = 0.f;
        #pragma unroll
        for (int g = 0; g < CGRP; ++g) s += pbase[g * NPQ + i];
        float val = s * (1.0f / 36.0f);
        acc[n * NPQ + i] = val;
        double dv = (double)val;
        ls += dv; ls2 += dv * dv;
    }
    #pragma unroll
    for (int off = 32; off > 0; off >>= 1) {
        ls  += __shfl_down(ls,  off, 64);
        ls2 += __shfl_down(ls2, off, 64);
    }
    if ((t & 63) == 0) { sred[(t >> 6) * 2] = ls; sred[(t >> 6) * 2 + 1] = ls2; }
    __syncthreads();
    if (t == 0) {
        double S = 0.0, S2 = 0.0;
        #pragma unroll
        for (int wv = 0; wv < 4; ++wv) { S += sred[2*wv]; S2 += sred[2*wv+1]; }
        dstat[2*n] = S; dstat[2*n+1] = S2;
    }
    __threadfence();
    __syncthreads();
    if (t == 0) flag = (atomicAdd(&cnt[16], 1u) == NB - 1) ? 1 : 0;
    __syncthreads();
    if (!flag) return;
    __threadfence();   // acquire

    // ---------------- phase 3: global BN + output ----------------
    double S = 0.0, S2 = 0.0;
    if (t < NB) { S = dstat[2*t]; S2 = dstat[2*t+1]; }
    #pragma unroll
    for (int off = 8; off > 0; off >>= 1) {
        S  += __shfl_down(S,  off, 64);
        S2 += __shfl_down(S2, off, 64);
    }
    if (t == 0) {
        double mu  = S / (double)TOT;
        double var = S2 / (double)TOT - mu * mu;
        fstat[0] = (float)mu;
        fstat[1] = (float)(1.0 / sqrt(var + 1e-5)) * bnw[0];
    }
    __syncthreads();
    const float mu    = fstat[0];
    const float scale = fstat[1];
    const float bias  = bnb[0];
    const float4* a4 = reinterpret_cast<const float4*>(acc);
    float4* o4 = reinterpret_cast<float4*>(out);
    for (int i = t; i < TOT / 4; i += 256) {      // 1156 float4
        float4 v = a4[i];
        v.x = (v.x - mu) * scale + bias;
        v.y = (v.y - mu) * scale + bias;
        v.z = (v.z - mu) * scale + bias;
        v.w = (v.w - mu) * scale + bias;
        o4[i] = v;
    }
}

extern "C" void kernel_launch(void* const* d_in, const int* in_sizes, int n_in,
                              void* d_out, int out_size, void* d_ws, size_t ws_size,
                              hipStream_t stream) {
    const float* z   = (const float*)d_in[0];   // [16,256,6,6]
    const float* x   = (const float*)d_in[1];   // [16,256,22,22]
    const float* w   = (const float*)d_in[2];   // [1,256,1,1,1] -> 256
    const float* bnw = (const float*)d_in[3];   // [1]
    const float* bnb = (const float*)d_in[4];   // [1]
    float* out = (float*)d_out;                 // [16,1,17,17] -> 4624
    float* ws  = (float*)d_ws;

    // zero the 17 arrival counters (ws is poisoned 0xAA before every launch)
    hipMemsetAsync(ws, 0, 17 * sizeof(unsigned int), stream);

    fused_kernel<<<NB * CGRP, 256, 0, stream>>>(z, x, w, bnw, bnb, ws, out);
}

// Round 4
// 76.207 us; speedup vs baseline: 1.6690x; 1.6690x over previous
//
#include <hip/hip_runtime.h>

// Problem constants: N=16, C=256, K=6, M=22, Ho=17
#define NB   16
#define CC   256
#define KK   6
#define MM   22
#define HO   17           // M - K + 1
#define NPQ  (HO*HO)      // 289 outputs per batch image
#define TOT  (NB*NPQ)     // 4624 total outputs
#define CHN  8            // channels per block
#define CGRP (CC/CHN)     // 32 channel-groups
#define XPC  (MM*MM)      // 484 x-elements per channel
#define ZPC  (KK*KK)      // 36 z-elements per channel
#define XSTR 24           // padded LDS row stride (16B-aligned rows)
#define XCH  548          // padded LDS channel stride: %32==4 (bank spread), %4==0
#define RCH  292          // reduction buffer channel stride: %32==4

// Kernel A: per-(batch, channel-group) correlation, register-tiled.
// Accumulates pre-scaled sums directly into acc[4624] via atomicAdd.
// NO device-scope fences (round-3 lesson: 512 blocks x __threadfence = ~60us L2 drain).
__global__ __launch_bounds__(256) void corr_kernel(
    const float* __restrict__ z, const float* __restrict__ x,
    const float* __restrict__ w, float* __restrict__ acc)
{
    __shared__ float szw[CHN * ZPC];    // w_c * sqrt(z)
    __shared__ float sx [CHN * XCH];    // sqrt(x), padded
    __shared__ float red[CHN * RCH];    // per-channel row results

    const int b  = blockIdx.x;
    const int n  = b >> 5;              // / CGRP
    const int cg = b & 31;              // % CGRP
    const int c0 = cg * CHN;
    const int t  = threadIdx.x;

    const float* zb = z + (size_t)(n * CC + c0) * ZPC;
    const float* xb = x + (size_t)(n * CC + c0) * XPC;

    // Stage w*sqrt(z): 288 contiguous floats
    for (int e = t; e < CHN * ZPC; e += 256) {
        int c = e / ZPC;
        szw[e] = sqrtf(zb[e]) * w[c0 + c];
    }
    // Stage sqrt(x) into padded rows (float2: odd global rows are 8B-aligned)
    {
        const float2* xb2 = reinterpret_cast<const float2*>(xb);
        for (int e = t; e < CHN * XPC / 2; e += 256) {   // 1936 float2
            int ch  = e / 242;
            int r   = e - ch * 242;
            int row = r / 11;
            int col = (r - row * 11) * 2;
            float2 v = xb2[e];
            float* dst = &sx[ch * XCH + row * XSTR + col];
            dst[0] = sqrtf(v.x);
            dst[1] = sqrtf(v.y);
        }
    }
    __syncthreads();

    if (t < HO * CHN) {                 // 136 active threads
        const int p  = t >> 3;          // 0..16
        const int ch = t & 7;

        // z fragment -> registers (9 b128)
        float zr[36];
        const float4* z4 = reinterpret_cast<const float4*>(&szw[ch * ZPC]);
        #pragma unroll
        for (int k = 0; k < 9; ++k) {
            float4 v = z4[k];
            zr[4*k] = v.x; zr[4*k+1] = v.y; zr[4*k+2] = v.z; zr[4*k+3] = v.w;
        }

        float a[HO];
        #pragma unroll
        for (int q = 0; q < HO; ++q) a[q] = 0.f;

        #pragma unroll
        for (int i = 0; i < KK; ++i) {
            float xr[24];
            const float4* row4 =
                reinterpret_cast<const float4*>(&sx[ch * XCH + (p + i) * XSTR]);
            #pragma unroll
            for (int k = 0; k < 6; ++k) {
                float4 v = row4[k];
                xr[4*k] = v.x; xr[4*k+1] = v.y; xr[4*k+2] = v.z; xr[4*k+3] = v.w;
            }
            #pragma unroll
            for (int j = 0; j < KK; ++j) {
                float zv = zr[i * KK + j];
                #pragma unroll
                for (int q = 0; q < HO; ++q)
                    a[q] += zv * xr[q + j];
            }
        }
        float* rr = &red[ch * RCH + p * HO];
        #pragma unroll
        for (int q = 0; q < HO; ++q) rr[q] = a[q];
    }
    __syncthreads();

    // Sum the 8 channels, pre-scale by 1/36, atomically accumulate into acc.
    // 289 coalesced wave-atomics per block; 32 blocks contend per address.
    float* ab = acc + n * NPQ;
    for (int idx = t; idx < NPQ; idx += 256) {
        float s = 0.f;
        #pragma unroll
        for (int ch = 0; ch < CHN; ++ch) s += red[ch * RCH + idx];
        atomicAdd(&ab[idx], s * (1.0f / 36.0f));
    }
}

// Kernel B: read acc (18.5 KB), double-precision stats, normalize, write out.
__global__ __launch_bounds__(512) void bn_kernel(
    const float* __restrict__ acc, const float* __restrict__ bnw,
    const float* __restrict__ bnb, float* __restrict__ out)
{
    __shared__ float  sacc[TOT];        // 18.5 KB value cache
    __shared__ double sred[16];
    __shared__ float  fstat[2];
    const int t = threadIdx.x;

    const float4* a4 = reinterpret_cast<const float4*>(acc);
    float4* s4 = reinterpret_cast<float4*>(sacc);
    double ls = 0.0, ls2 = 0.0;
    for (int i = t; i < TOT / 4; i += 512) {     // 1156 float4
        float4 v = a4[i];
        s4[i] = v;
        double dx = v.x, dy = v.y, dz = v.z, dw = v.w;
        ls  += (dx + dy) + (dz + dw);
        ls2 += (dx * dx + dy * dy) + (dz * dz + dw * dw);
    }
    #pragma unroll
    for (int off = 32; off > 0; off >>= 1) {
        ls  += __shfl_down(ls,  off, 64);
        ls2 += __shfl_down(ls2, off, 64);
    }
    if ((t & 63) == 0) { sred[(t >> 6) * 2] = ls; sred[(t >> 6) * 2 + 1] = ls2; }
    __syncthreads();
    if (t == 0) {
        double S = 0.0, S2 = 0.0;
        #pragma unroll
        for (int wv = 0; wv < 8; ++wv) { S += sred[2 * wv]; S2 += sred[2 * wv + 1]; }
        double mu  = S / (double)TOT;
        double var = S2 / (double)TOT - mu * mu;
        fstat[0] = (float)mu;
        fstat[1] = (float)(1.0 / sqrt(var + 1e-5)) * bnw[0];
    }
    __syncthreads();

    const float mu    = fstat[0];
    const float scale = fstat[1];
    const float bias  = bnb[0];
    float4* o4 = reinterpret_cast<float4*>(out);
    for (int i = t; i < TOT / 4; i += 512) {
        float4 v = s4[i];
        v.x = (v.x - mu) * scale + bias;
        v.y = (v.y - mu) * scale + bias;
        v.z = (v.z - mu) * scale + bias;
        v.w = (v.w - mu) * scale + bias;
        o4[i] = v;
    }
}

extern "C" void kernel_launch(void* const* d_in, const int* in_sizes, int n_in,
                              void* d_out, int out_size, void* d_ws, size_t ws_size,
                              hipStream_t stream) {
    const float* z   = (const float*)d_in[0];   // [16,256,6,6]
    const float* x   = (const float*)d_in[1];   // [16,256,22,22]
    const float* w   = (const float*)d_in[2];   // [1,256,1,1,1] -> 256
    const float* bnw = (const float*)d_in[3];   // [1]
    const float* bnb = (const float*)d_in[4];   // [1]
    float* out = (float*)d_out;                 // [16,1,17,17] -> 4624
    float* acc = (float*)d_ws;                  // 4624-float accumulator

    // acc is poisoned 0xAA before every launch — zero it (18.5 KB, cheap fill)
    hipMemsetAsync(acc, 0, TOT * sizeof(float), stream);

    corr_kernel<<<NB * CGRP, 256, 0, stream>>>(z, x, w, acc);
    bn_kernel<<<1, 512, 0, stream>>>(acc, bnw, bnb, out);
}